// Round 4
// baseline (450.320 us; speedup 1.0000x reference)
//
#include <hip/hip_runtime.h>

typedef unsigned short u16;
typedef __bf16 bf16;
typedef float f32x4 __attribute__((ext_vector_type(4)));
typedef bf16 bf16x8 __attribute__((ext_vector_type(8)));
typedef short s16x4 __attribute__((ext_vector_type(4)));
typedef u16 u16x4 __attribute__((ext_vector_type(4)));
typedef u16 u16x8 __attribute__((ext_vector_type(8)));

#define SEQ 2048
#define LOG2E 1.4426950408889634f

__device__ __forceinline__ u16 f2bf(float f) {
    return __builtin_bit_cast(u16, (bf16)f);
}
__device__ __forceinline__ float bf2f(u16 u) {
    unsigned int w = ((unsigned int)u) << 16;
    return __builtin_bit_cast(float, w);
}

// ---------------- cast f32 -> bf16 (vectorized) ----------------
__global__ __launch_bounds__(256) void cast_bf16_k(const float* __restrict__ in,
                                                   u16* __restrict__ out, int n4) {
    int i = blockIdx.x * 256 + threadIdx.x;
    int stride = gridDim.x * 256;
    for (; i < n4; i += stride) {
        float4 v = reinterpret_cast<const float4*>(in)[i];
        u16x4 o;
        o[0] = f2bf(v.x); o[1] = f2bf(v.y); o[2] = f2bf(v.z); o[3] = f2bf(v.w);
        reinterpret_cast<u16x4*>(out)[i] = o;
    }
}

// ---------------- transpose + cast: src f32 [R][C] -> dst bf16 [C][R] ----------------
__global__ __launch_bounds__(256) void transpose_cast_k(const float* __restrict__ src,
                                                        u16* __restrict__ dst, int R, int C) {
    __shared__ float t[64][65];
    int c0 = blockIdx.x * 64, r0 = blockIdx.y * 64;
    int tx = threadIdx.x & 63, ty = threadIdx.x >> 6;
#pragma unroll
    for (int i = 0; i < 16; ++i) {
        int r = ty + i * 4;
        t[r][tx] = src[(size_t)(r0 + r) * C + c0 + tx];
    }
    __syncthreads();
#pragma unroll
    for (int i = 0; i < 16; ++i) {
        int c = ty + i * 4;
        dst[(size_t)(c0 + c) * R + r0 + tx] = f2bf(t[tx][c]);
    }
}

// ---------------- GEMM: C[M,N] = A[M,K] @ Bt[N,K]^T, bf16 in, f32 out ----------------
__global__ __launch_bounds__(256) void gemm_bt_k(const u16* __restrict__ A,
                                                 const u16* __restrict__ Bt,
                                                 float* __restrict__ C,
                                                 int M, int N, int K) {
    __shared__ __align__(16) u16 As[128 * 32];
    __shared__ __align__(16) u16 Bs[128 * 32];
    int tid = threadIdx.x;
    int wave = tid >> 6, lane = tid & 63;
    int bm = blockIdx.y * 128, bn = blockIdx.x * 128;
    int wm = (wave >> 1) * 64, wn = (wave & 1) * 64;
    int g = lane >> 4, cidx = lane & 15;
    f32x4 acc[4][4] = {};

    int srow = (lane >> 2);
    int skol = (lane & 3) * 8;

    for (int kt = 0; kt < K; kt += 32) {
#pragma unroll
        for (int j = 0; j < 2; ++j) {
            const u16* gp = A + (size_t)(bm + (wave * 2 + j) * 16 + srow) * K + kt + skol;
            __builtin_amdgcn_global_load_lds(
                (__attribute__((address_space(1))) void*)gp,
                (__attribute__((address_space(3))) void*)&As[(wave * 2 + j) * 512],
                16, 0, 0);
        }
#pragma unroll
        for (int j = 0; j < 2; ++j) {
            const u16* gp = Bt + (size_t)(bn + (wave * 2 + j) * 16 + srow) * K + kt + skol;
            __builtin_amdgcn_global_load_lds(
                (__attribute__((address_space(1))) void*)gp,
                (__attribute__((address_space(3))) void*)&Bs[(wave * 2 + j) * 512],
                16, 0, 0);
        }
        asm volatile("s_waitcnt vmcnt(0)" ::: "memory");
        __syncthreads();

        bf16x8 af[4], bfr[4];
#pragma unroll
        for (int mi = 0; mi < 4; ++mi)
            af[mi] = *reinterpret_cast<const bf16x8*>(&As[(wm + mi * 16 + cidx) * 32 + g * 8]);
#pragma unroll
        for (int ni = 0; ni < 4; ++ni)
            bfr[ni] = *reinterpret_cast<const bf16x8*>(&Bs[(wn + ni * 16 + cidx) * 32 + g * 8]);
#pragma unroll
        for (int mi = 0; mi < 4; ++mi)
#pragma unroll
            for (int ni = 0; ni < 4; ++ni)
                acc[mi][ni] = __builtin_amdgcn_mfma_f32_16x16x32_bf16(af[mi], bfr[ni], acc[mi][ni], 0, 0, 0);
        __syncthreads();
    }

#pragma unroll
    for (int mi = 0; mi < 4; ++mi) {
#pragma unroll
        for (int r = 0; r < 4; ++r) {
            int row = bm + wm + mi * 16 + g * 4 + r;
            float* cp = C + (size_t)row * N + bn + wn + cidx;
#pragma unroll
            for (int ni = 0; ni < 4; ++ni)
                cp[ni * 16] = acc[mi][ni][r];
        }
    }
}

// ---------------- RMSNorm + RoPE for Q and K heads ----------------
// Q: pre-scaled by 0.125*log2(e) (exp2-base softmax), row-major [s][32*64]
// K: written in MFMA A-fragment order kfrag[kvh][kb=s>>4][g=d>>3][c=s&15][e=d&7]
__global__ __launch_bounds__(256) void norm_rope_k(const float* __restrict__ qkv,
                                                   const float* __restrict__ cosb,
                                                   const float* __restrict__ sinb,
                                                   const float* __restrict__ qw,
                                                   const float* __restrict__ kw,
                                                   u16* __restrict__ qn,
                                                   u16* __restrict__ kfrag) {
    int idx = blockIdx.x * 4 + (threadIdx.x >> 6);
    int lane = threadIdx.x & 63;
    int s = idx / 40, hh = idx - s * 40;
    float val;
    if (hh < 32) val = qkv[(size_t)s * 3072 + hh * 64 + lane];
    else         val = qkv[(size_t)s * 3072 + 2048 + (hh - 32) * 64 + lane];
    float ss = val * val;
#pragma unroll
    for (int mm = 32; mm; mm >>= 1) ss += __shfl_xor(ss, mm);
    float w = (hh < 32) ? qw[lane] : kw[lane];
    float xn = val * rsqrtf(ss * (1.f / 64.f) + 1e-6f) * w;
    float part = __shfl_xor(xn, 32);
    float rot = (lane < 32) ? -part : part;
    float o = xn * cosb[s * 64 + lane] + rot * sinb[s * 64 + lane];
    if (hh < 32) {
        qn[(size_t)s * 2048 + hh * 64 + lane] = f2bf(o * (0.125f * LOG2E));
    } else {
        int h8 = hh - 32;
        kfrag[(((size_t)h8 * 128 + (s >> 4)) << 10) + (lane >> 3) * 128 + (s & 15) * 8 + (lane & 7)] = f2bf(o);
    }
}

// ---------------- V in packed PV A-fragment order ----------------
// vfrag[kvh][kb32][dt][g][c][s2*4+i] = V[kb32*32 + s2*16 + g*4 + i][dt*16 + c]
__global__ __launch_bounds__(256) void v_frag_k(const float* __restrict__ qkv,
                                                u16* __restrict__ vfrag) {
    __shared__ float t[64][65];
    int s0 = blockIdx.x * 64;
    int h = blockIdx.y;
    int tx = threadIdx.x & 63, ty = threadIdx.x >> 6;
#pragma unroll
    for (int i = 0; i < 16; ++i) {
        int r = ty + i * 4;
        t[r][tx] = qkv[(size_t)(s0 + r) * 3072 + 2560 + h * 64 + tx];
    }
    __syncthreads();
    int dt = threadIdx.x >> 6, g = (threadIdx.x >> 4) & 3, cc = threadIdx.x & 15;
#pragma unroll
    for (int kb2 = 0; kb2 < 4; ++kb2) {
        u16x4 o;
#pragma unroll
        for (int i = 0; i < 4; ++i) o[i] = f2bf(t[kb2 * 16 + g * 4 + i][dt * 16 + cc]);
        size_t idx = ((size_t)h * 64 + (s0 >> 5) + (kb2 >> 1)) * 2048 + dt * 512 + g * 128 + cc * 8 + (kb2 & 1) * 4;
        *reinterpret_cast<u16x4*>(&vfrag[idx]) = o;
    }
}

// ---------------- Flash attention: dense (chunk,window) wave enumeration ----------------
// Per head: 320 active waves, j -> (c,w) analytically (windows of 512 keys).
// Each wave writes a private 16x64 bf16 partial slot + 16 f32 l-partials (no atomics).
__global__ __launch_bounds__(256, 8) void attn_k(const u16* __restrict__ qn,
                                                 const u16* __restrict__ kfrag,
                                                 const u16* __restrict__ vfrag,
                                                 u16* __restrict__ obuf,
                                                 float* __restrict__ lbuf) {
    int h = blockIdx.x;
    int wave = threadIdx.x >> 6, lane = threadIdx.x & 63;
    int j = blockIdx.y * 4 + wave;   // 0..319
    int c, w;
    if (j < 32)       { c = j;                    w = 0; }
    else if (j < 96)  { c = 32 + ((j - 32) >> 1); w = (j - 32) & 1; }
    else if (j < 192) { int r = j - 96;  int q = r / 3; c = 64 + q; w = r - 3 * q; }
    else              { c = 96 + ((j - 192) >> 2); w = (j - 192) & 3; }

    int q0 = c * 16;
    int nk = q0 + 16;
    int kv0 = w * 512;
    int kvend = (kv0 + 512 < nk) ? (kv0 + 512) : nk;

    int kvh = h >> 2, g = lane >> 4, cc = lane & 15;
    int qrow = q0 + cc;

    const size_t qoff = (size_t)qrow * 2048 + h * 64;
    bf16x8 q_0 = *reinterpret_cast<const bf16x8*>(&qn[qoff + g * 8]);
    bf16x8 q_1 = *reinterpret_cast<const bf16x8*>(&qn[qoff + 32 + g * 8]);

    float l = 0.f;
    f32x4 o[4] = {};

    const u16* kbase = kfrag + (((size_t)kvh * 128) << 10) + lane * 8;
    const u16* vbase = vfrag + (size_t)kvh * 64 * 2048 + g * 128 + cc * 8;

    // preload K for first block
    bf16x8 kf0[4], kf1[4];
#pragma unroll
    for (int sub = 0; sub < 4; ++sub) {
        const u16* kp = kbase + (size_t)((kv0 >> 4) + sub) * 1024;
        kf0[sub] = *reinterpret_cast<const bf16x8*>(kp);
        kf1[sub] = *reinterpret_cast<const bf16x8*>(kp + 512);
    }

#pragma unroll 1
    for (; kv0 < kvend; kv0 += 64) {
        f32x4 st[4];
        __builtin_amdgcn_s_setprio(1);
#pragma unroll
        for (int sub = 0; sub < 4; ++sub) {
            st[sub] = __builtin_amdgcn_mfma_f32_16x16x32_bf16(kf0[sub], q_0, (f32x4){0.f, 0.f, 0.f, 0.f}, 0, 0, 0);
            st[sub] = __builtin_amdgcn_mfma_f32_16x16x32_bf16(kf1[sub], q_1, st[sub], 0, 0, 0);
        }
        __builtin_amdgcn_s_setprio(0);

        // K prefetch for next block (in-flight across softmax)
        if (kv0 + 64 < kvend) {
#pragma unroll
            for (int sub = 0; sub < 4; ++sub) {
                const u16* kp = kbase + (size_t)(((kv0 + 64) >> 4) + sub) * 1024;
                kf0[sub] = *reinterpret_cast<const bf16x8*>(kp);
                kf1[sub] = *reinterpret_cast<const bf16x8*>(kp + 512);
            }
        }

        // V loads for current block
        bf16x8 vv[2][4];
#pragma unroll
        for (int sp = 0; sp < 2; ++sp)
#pragma unroll
            for (int dt = 0; dt < 4; ++dt)
                vv[sp][dt] = *reinterpret_cast<const bf16x8*>(
                    vbase + (size_t)((kv0 >> 5) + sp) * 2048 + dt * 512);

        // causal mask (diagonal block only)
        if (kv0 + 64 > q0) {
#pragma unroll
            for (int sub = 0; sub < 4; ++sub)
#pragma unroll
                for (int r = 0; r < 4; ++r)
                    if (kv0 + sub * 16 + g * 4 + r > qrow) st[sub][r] = -1e30f;
        }

        // fixed-base softmax: weights = exp2(score'), no max tracking
        s16x4 pf[4];
        float rs = 0.f;
#pragma unroll
        for (int sub = 0; sub < 4; ++sub)
#pragma unroll
            for (int r = 0; r < 4; ++r) {
                float e = __builtin_amdgcn_exp2f(st[sub][r]);
                rs += e;
                pf[sub][r] = (short)f2bf(e);
            }
        l += rs;

        __builtin_amdgcn_s_setprio(1);
#pragma unroll
        for (int sp = 0; sp < 2; ++sp)
#pragma unroll
            for (int dt = 0; dt < 4; ++dt) {
                s16x4 vlo = __builtin_bit_cast(s16x4,
                    __builtin_shufflevector(vv[sp][dt], vv[sp][dt], 0, 1, 2, 3));
                s16x4 vhi = __builtin_bit_cast(s16x4,
                    __builtin_shufflevector(vv[sp][dt], vv[sp][dt], 4, 5, 6, 7));
                o[dt] = __builtin_amdgcn_mfma_f32_16x16x16bf16_1k(vlo, pf[sp * 2], o[dt], 0, 0, 0);
                o[dt] = __builtin_amdgcn_mfma_f32_16x16x16bf16_1k(vhi, pf[sp * 2 + 1], o[dt], 0, 0, 0);
            }
        __builtin_amdgcn_s_setprio(0);
    }

    // private-slot partial write (plain stores, no atomics)
    l += __shfl_xor(l, 16);
    l += __shfl_xor(l, 32);
    size_t slot = (size_t)h * 320 + j;
    if (lane < 16) lbuf[slot * 16 + cc] = l;
    u16* sp = obuf + slot * 1024;
#pragma unroll
    for (int dt = 0; dt < 4; ++dt) {
        u16x4 ov;
#pragma unroll
        for (int r = 0; r < 4; ++r) ov[r] = f2bf(o[dt][r]);
        *reinterpret_cast<u16x4*>(&sp[cc * 64 + dt * 16 + g * 4]) = ov;
    }
}

// ---------------- merge: attn_bf16 = sum(o_w) / (sum(l_w) + 2^(sink*log2e)) ----------------
__global__ __launch_bounds__(256) void merge_k(const u16* __restrict__ obuf,
                                               const float* __restrict__ lbuf,
                                               const float* __restrict__ sink,
                                               u16* __restrict__ attnb) {
    int row = blockIdx.x;
    int c = row >> 4, cc = row & 15;
    int nw = (c >> 5) + 1;  // windows for this chunk
    int jb = (c < 32) ? c
           : (c < 64) ? 32 + ((c - 32) << 1)
           : (c < 96) ? 96 + 3 * (c - 64)
                      : 192 + ((c - 96) << 2);
    int t = threadIdx.x;
    int h = t >> 3, col0 = (t & 7) * 8;

    float acc[8] = {};
    float lsum = __builtin_amdgcn_exp2f(sink[h] * LOG2E);
#pragma unroll 1
    for (int w = 0; w < nw; ++w) {
        size_t slot = (size_t)h * 320 + jb + w;
        lsum += lbuf[slot * 16 + cc];
        u16x8 v = *reinterpret_cast<const u16x8*>(&obuf[slot * 1024 + cc * 64 + col0]);
#pragma unroll
        for (int i = 0; i < 8; ++i) acc[i] += bf2f(v[i]);
    }
    float inv = 1.f / lsum;
    u16x8 ob;
#pragma unroll
    for (int i = 0; i < 8; ++i) ob[i] = f2bf(acc[i] * inv);
    *reinterpret_cast<u16x8*>(&attnb[(size_t)row * 2048 + h * 64 + col0]) = ob;
}

extern "C" void kernel_launch(void* const* d_in, const int* in_sizes, int n_in,
                              void* d_out, int out_size, void* d_ws, size_t ws_size,
                              hipStream_t stream) {
    const float* x    = (const float*)d_in[0];
    const float* cosb = (const float*)d_in[2];
    const float* sinb = (const float*)d_in[3];
    const float* wq   = (const float*)d_in[4];
    const float* wk   = (const float*)d_in[5];
    const float* wv   = (const float*)d_in[6];
    const float* wo   = (const float*)d_in[7];
    const float* qw   = (const float*)d_in[8];
    const float* kw   = (const float*)d_in[9];
    const float* sink = (const float*)d_in[10];
    float* out = (float*)d_out;

    char* ws = (char*)d_ws;
    size_t off = 0;
    auto alloc = [&](size_t bytes) {
        char* p = ws + off;
        off += (bytes + 255) & ~(size_t)255;
        return p;
    };
    u16*   xb    = (u16*)alloc((size_t)2048 * 2048 * 2);
    u16*   wqkvt = (u16*)alloc((size_t)3072 * 2048 * 2);
    u16*   wot   = (u16*)alloc((size_t)2048 * 2048 * 2);
    float* qkv   = (float*)alloc((size_t)2048 * 3072 * 4);
    u16*   qnb   = (u16*)alloc((size_t)2048 * 2048 * 2);
    u16*   kfrag = (u16*)alloc((size_t)8 * 128 * 1024 * 2);
    u16*   vfrag = (u16*)alloc((size_t)8 * 64 * 2048 * 2);
    float* lbuf  = (float*)alloc((size_t)32 * 320 * 16 * 4);
    u16*   attnb = xb;              // xb dead after GEMM1
    u16*   obuf  = (u16*)qkv;       // qkv (25 MB) dead after norm_rope/v_frag; slots need 21 MB

    cast_bf16_k<<<2048, 256, 0, stream>>>(x, xb, 2048 * 2048 / 4);
    transpose_cast_k<<<dim3(32, 32), 256, 0, stream>>>(wq, wqkvt, 2048, 2048);
    transpose_cast_k<<<dim3(8, 32), 256, 0, stream>>>(wk, wqkvt + (size_t)2048 * 2048, 2048, 512);
    transpose_cast_k<<<dim3(8, 32), 256, 0, stream>>>(wv, wqkvt + (size_t)2560 * 2048, 2048, 512);
    transpose_cast_k<<<dim3(32, 32), 256, 0, stream>>>(wo, wot, 2048, 2048);

    gemm_bt_k<<<dim3(24, 16), 256, 0, stream>>>(xb, wqkvt, qkv, 2048, 3072, 2048);
    norm_rope_k<<<20480, 256, 0, stream>>>(qkv, cosb, sinb, qw, kw, qnb, kfrag);
    v_frag_k<<<dim3(32, 8), 256, 0, stream>>>(qkv, vfrag);

    attn_k<<<dim3(32, 80), 256, 0, stream>>>(qnb, kfrag, vfrag, obuf, lbuf);
    merge_k<<<2048, 256, 0, stream>>>(obuf, lbuf, sink, attnb);

    gemm_bt_k<<<dim3(16, 16), 256, 0, stream>>>(attnb, wot, out, 2048, 2048, 2048);
}

// Round 5
// 195.121 us; speedup vs baseline: 2.3079x; 2.3079x over previous
//
#include <hip/hip_runtime.h>

typedef unsigned short u16;
typedef __bf16 bf16;
typedef float f32x4 __attribute__((ext_vector_type(4)));
typedef bf16 bf16x8 __attribute__((ext_vector_type(8)));
typedef short s16x4 __attribute__((ext_vector_type(4)));
typedef u16 u16x4 __attribute__((ext_vector_type(4)));
typedef u16 u16x8 __attribute__((ext_vector_type(8)));

#define SEQ 2048
#define LOG2E 1.4426950408889634f

__device__ __forceinline__ u16 f2bf(float f) {
    return __builtin_bit_cast(u16, (bf16)f);
}
__device__ __forceinline__ float bf2f(u16 u) {
    unsigned int w = ((unsigned int)u) << 16;
    return __builtin_bit_cast(float, w);
}

// ---------------- cast f32 -> bf16 (vectorized) ----------------
__global__ __launch_bounds__(256) void cast_bf16_k(const float* __restrict__ in,
                                                   u16* __restrict__ out, int n4) {
    int i = blockIdx.x * 256 + threadIdx.x;
    int stride = gridDim.x * 256;
    for (; i < n4; i += stride) {
        float4 v = reinterpret_cast<const float4*>(in)[i];
        u16x4 o;
        o[0] = f2bf(v.x); o[1] = f2bf(v.y); o[2] = f2bf(v.z); o[3] = f2bf(v.w);
        reinterpret_cast<u16x4*>(out)[i] = o;
    }
}

// ---------------- transpose + cast: src f32 [R][C] -> dst bf16 [C][R] ----------------
__global__ __launch_bounds__(256) void transpose_cast_k(const float* __restrict__ src,
                                                        u16* __restrict__ dst, int R, int C) {
    __shared__ float t[64][65];
    int c0 = blockIdx.x * 64, r0 = blockIdx.y * 64;
    int tx = threadIdx.x & 63, ty = threadIdx.x >> 6;
#pragma unroll
    for (int i = 0; i < 16; ++i) {
        int r = ty + i * 4;
        t[r][tx] = src[(size_t)(r0 + r) * C + c0 + tx];
    }
    __syncthreads();
#pragma unroll
    for (int i = 0; i < 16; ++i) {
        int c = ty + i * 4;
        dst[(size_t)(c0 + c) * R + r0 + tx] = f2bf(t[tx][c]);
    }
}

// ---------------- GEMM: C[M,N] = A[M,K] @ Bt[N,K]^T, bf16 in, f32 out ----------------
__global__ __launch_bounds__(256) void gemm_bt_k(const u16* __restrict__ A,
                                                 const u16* __restrict__ Bt,
                                                 float* __restrict__ C,
                                                 int M, int N, int K) {
    __shared__ __align__(16) u16 As[128 * 32];
    __shared__ __align__(16) u16 Bs[128 * 32];
    int tid = threadIdx.x;
    int wave = tid >> 6, lane = tid & 63;
    int bm = blockIdx.y * 128, bn = blockIdx.x * 128;
    int wm = (wave >> 1) * 64, wn = (wave & 1) * 64;
    int g = lane >> 4, cidx = lane & 15;
    f32x4 acc[4][4] = {};

    int srow = (lane >> 2);
    int skol = (lane & 3) * 8;

    for (int kt = 0; kt < K; kt += 32) {
#pragma unroll
        for (int j = 0; j < 2; ++j) {
            const u16* gp = A + (size_t)(bm + (wave * 2 + j) * 16 + srow) * K + kt + skol;
            __builtin_amdgcn_global_load_lds(
                (__attribute__((address_space(1))) void*)gp,
                (__attribute__((address_space(3))) void*)&As[(wave * 2 + j) * 512],
                16, 0, 0);
        }
#pragma unroll
        for (int j = 0; j < 2; ++j) {
            const u16* gp = Bt + (size_t)(bn + (wave * 2 + j) * 16 + srow) * K + kt + skol;
            __builtin_amdgcn_global_load_lds(
                (__attribute__((address_space(1))) void*)gp,
                (__attribute__((address_space(3))) void*)&Bs[(wave * 2 + j) * 512],
                16, 0, 0);
        }
        asm volatile("s_waitcnt vmcnt(0)" ::: "memory");
        __syncthreads();

        bf16x8 af[4], bfr[4];
#pragma unroll
        for (int mi = 0; mi < 4; ++mi)
            af[mi] = *reinterpret_cast<const bf16x8*>(&As[(wm + mi * 16 + cidx) * 32 + g * 8]);
#pragma unroll
        for (int ni = 0; ni < 4; ++ni)
            bfr[ni] = *reinterpret_cast<const bf16x8*>(&Bs[(wn + ni * 16 + cidx) * 32 + g * 8]);
#pragma unroll
        for (int mi = 0; mi < 4; ++mi)
#pragma unroll
            for (int ni = 0; ni < 4; ++ni)
                acc[mi][ni] = __builtin_amdgcn_mfma_f32_16x16x32_bf16(af[mi], bfr[ni], acc[mi][ni], 0, 0, 0);
        __syncthreads();
    }

#pragma unroll
    for (int mi = 0; mi < 4; ++mi) {
#pragma unroll
        for (int r = 0; r < 4; ++r) {
            int row = bm + wm + mi * 16 + g * 4 + r;
            float* cp = C + (size_t)row * N + bn + wn + cidx;
#pragma unroll
            for (int ni = 0; ni < 4; ++ni)
                cp[ni * 16] = acc[mi][ni][r];
        }
    }
}

// ---------------- RMSNorm + RoPE for Q and K heads ----------------
// Q: pre-scaled by 0.125*log2(e) (exp2-base softmax), row-major [s][32*64]
// K: written in MFMA A-fragment order kfrag[kvh][kb=s>>4][g=d>>3][c=s&15][e=d&7]
__global__ __launch_bounds__(256) void norm_rope_k(const float* __restrict__ qkv,
                                                   const float* __restrict__ cosb,
                                                   const float* __restrict__ sinb,
                                                   const float* __restrict__ qw,
                                                   const float* __restrict__ kw,
                                                   u16* __restrict__ qn,
                                                   u16* __restrict__ kfrag) {
    int idx = blockIdx.x * 4 + (threadIdx.x >> 6);
    int lane = threadIdx.x & 63;
    int s = idx / 40, hh = idx - s * 40;
    float val;
    if (hh < 32) val = qkv[(size_t)s * 3072 + hh * 64 + lane];
    else         val = qkv[(size_t)s * 3072 + 2048 + (hh - 32) * 64 + lane];
    float ss = val * val;
#pragma unroll
    for (int mm = 32; mm; mm >>= 1) ss += __shfl_xor(ss, mm);
    float w = (hh < 32) ? qw[lane] : kw[lane];
    float xn = val * rsqrtf(ss * (1.f / 64.f) + 1e-6f) * w;
    float part = __shfl_xor(xn, 32);
    float rot = (lane < 32) ? -part : part;
    float o = xn * cosb[s * 64 + lane] + rot * sinb[s * 64 + lane];
    if (hh < 32) {
        qn[(size_t)s * 2048 + hh * 64 + lane] = f2bf(o * (0.125f * LOG2E));
    } else {
        int h8 = hh - 32;
        kfrag[(((size_t)h8 * 128 + (s >> 4)) << 10) + (lane >> 3) * 128 + (s & 15) * 8 + (lane & 7)] = f2bf(o);
    }
}

// ---------------- V in packed PV A-fragment order ----------------
// vfrag[kvh][kb32][dt][g][c][s2*4+i] = V[kb32*32 + s2*16 + g*4 + i][dt*16 + c]
__global__ __launch_bounds__(256) void v_frag_k(const float* __restrict__ qkv,
                                                u16* __restrict__ vfrag) {
    __shared__ float t[64][65];
    int s0 = blockIdx.x * 64;
    int h = blockIdx.y;
    int tx = threadIdx.x & 63, ty = threadIdx.x >> 6;
#pragma unroll
    for (int i = 0; i < 16; ++i) {
        int r = ty + i * 4;
        t[r][tx] = qkv[(size_t)(s0 + r) * 3072 + 2560 + h * 64 + tx];
    }
    __syncthreads();
    int dt = threadIdx.x >> 6, g = (threadIdx.x >> 4) & 3, cc = threadIdx.x & 15;
#pragma unroll
    for (int kb2 = 0; kb2 < 4; ++kb2) {
        u16x4 o;
#pragma unroll
        for (int i = 0; i < 4; ++i) o[i] = f2bf(t[kb2 * 16 + g * 4 + i][dt * 16 + cc]);
        size_t idx = ((size_t)h * 64 + (s0 >> 5) + (kb2 >> 1)) * 2048 + dt * 512 + g * 128 + cc * 8 + (kb2 & 1) * 4;
        *reinterpret_cast<u16x4*>(&vfrag[idx]) = o;
    }
}

// ---------------- Flash attention: dense (chunk,window) wave enumeration ----------------
// Per head: 320 active waves, j -> (c,w) analytically (windows of 512 keys).
// Each wave writes a private 16x64 bf16 partial slot + 16 f32 l-partials (no atomics).
// NOTE: launch_bounds min-waves MUST stay <=4: (256,8) capped VGPR at 32 and
// spilled ~1.3 GB of scratch to HBM per dispatch (round-4 regression).
__global__ __launch_bounds__(256, 4) void attn_k(const u16* __restrict__ qn,
                                                 const u16* __restrict__ kfrag,
                                                 const u16* __restrict__ vfrag,
                                                 u16* __restrict__ obuf,
                                                 float* __restrict__ lbuf) {
    int h = blockIdx.x;
    int wave = threadIdx.x >> 6, lane = threadIdx.x & 63;
    int j = blockIdx.y * 4 + wave;   // 0..319
    int c, w;
    if (j < 32)       { c = j;                    w = 0; }
    else if (j < 96)  { c = 32 + ((j - 32) >> 1); w = (j - 32) & 1; }
    else if (j < 192) { int r = j - 96;  int q = r / 3; c = 64 + q; w = r - 3 * q; }
    else              { c = 96 + ((j - 192) >> 2); w = (j - 192) & 3; }

    int q0 = c * 16;
    int nk = q0 + 16;
    int kv0 = w * 512;
    int kvend = (kv0 + 512 < nk) ? (kv0 + 512) : nk;

    int kvh = h >> 2, g = lane >> 4, cc = lane & 15;
    int qrow = q0 + cc;

    const size_t qoff = (size_t)qrow * 2048 + h * 64;
    bf16x8 q_0 = *reinterpret_cast<const bf16x8*>(&qn[qoff + g * 8]);
    bf16x8 q_1 = *reinterpret_cast<const bf16x8*>(&qn[qoff + 32 + g * 8]);

    float l = 0.f;
    f32x4 o[4] = {};

    const u16* kbase = kfrag + (((size_t)kvh * 128) << 10) + lane * 8;
    const u16* vbase = vfrag + (size_t)kvh * 64 * 2048 + g * 128 + cc * 8;

    // preload K for first block
    bf16x8 kf0[4], kf1[4];
#pragma unroll
    for (int sub = 0; sub < 4; ++sub) {
        const u16* kp = kbase + (size_t)((kv0 >> 4) + sub) * 1024;
        kf0[sub] = *reinterpret_cast<const bf16x8*>(kp);
        kf1[sub] = *reinterpret_cast<const bf16x8*>(kp + 512);
    }

#pragma unroll 1
    for (; kv0 < kvend; kv0 += 64) {
        f32x4 st[4];
        __builtin_amdgcn_s_setprio(1);
#pragma unroll
        for (int sub = 0; sub < 4; ++sub) {
            st[sub] = __builtin_amdgcn_mfma_f32_16x16x32_bf16(kf0[sub], q_0, (f32x4){0.f, 0.f, 0.f, 0.f}, 0, 0, 0);
            st[sub] = __builtin_amdgcn_mfma_f32_16x16x32_bf16(kf1[sub], q_1, st[sub], 0, 0, 0);
        }
        __builtin_amdgcn_s_setprio(0);

        // K prefetch for next block (in-flight across softmax)
        if (kv0 + 64 < kvend) {
#pragma unroll
            for (int sub = 0; sub < 4; ++sub) {
                const u16* kp = kbase + (size_t)(((kv0 + 64) >> 4) + sub) * 1024;
                kf0[sub] = *reinterpret_cast<const bf16x8*>(kp);
                kf1[sub] = *reinterpret_cast<const bf16x8*>(kp + 512);
            }
        }

        // V loads for current block
        bf16x8 vv[2][4];
#pragma unroll
        for (int sp = 0; sp < 2; ++sp)
#pragma unroll
            for (int dt = 0; dt < 4; ++dt)
                vv[sp][dt] = *reinterpret_cast<const bf16x8*>(
                    vbase + (size_t)((kv0 >> 5) + sp) * 2048 + dt * 512);

        // causal mask (diagonal block only)
        if (kv0 + 64 > q0) {
#pragma unroll
            for (int sub = 0; sub < 4; ++sub)
#pragma unroll
                for (int r = 0; r < 4; ++r)
                    if (kv0 + sub * 16 + g * 4 + r > qrow) st[sub][r] = -1e30f;
        }

        // fixed-base softmax: weights = exp2(score'), no max tracking
        s16x4 pf[4];
        float rs = 0.f;
#pragma unroll
        for (int sub = 0; sub < 4; ++sub)
#pragma unroll
            for (int r = 0; r < 4; ++r) {
                float e = __builtin_amdgcn_exp2f(st[sub][r]);
                rs += e;
                pf[sub][r] = (short)f2bf(e);
            }
        l += rs;

        __builtin_amdgcn_s_setprio(1);
#pragma unroll
        for (int sp = 0; sp < 2; ++sp)
#pragma unroll
            for (int dt = 0; dt < 4; ++dt) {
                s16x4 vlo = __builtin_bit_cast(s16x4,
                    __builtin_shufflevector(vv[sp][dt], vv[sp][dt], 0, 1, 2, 3));
                s16x4 vhi = __builtin_bit_cast(s16x4,
                    __builtin_shufflevector(vv[sp][dt], vv[sp][dt], 4, 5, 6, 7));
                o[dt] = __builtin_amdgcn_mfma_f32_16x16x16bf16_1k(vlo, pf[sp * 2], o[dt], 0, 0, 0);
                o[dt] = __builtin_amdgcn_mfma_f32_16x16x16bf16_1k(vhi, pf[sp * 2 + 1], o[dt], 0, 0, 0);
            }
        __builtin_amdgcn_s_setprio(0);
    }

    // private-slot partial write (plain stores, no atomics)
    l += __shfl_xor(l, 16);
    l += __shfl_xor(l, 32);
    size_t slot = (size_t)h * 320 + j;
    if (lane < 16) lbuf[slot * 16 + cc] = l;
    u16* sp = obuf + slot * 1024;
#pragma unroll
    for (int dt = 0; dt < 4; ++dt) {
        u16x4 ov;
#pragma unroll
        for (int r = 0; r < 4; ++r) ov[r] = f2bf(o[dt][r]);
        *reinterpret_cast<u16x4*>(&sp[cc * 64 + dt * 16 + g * 4]) = ov;
    }
}

// ---------------- merge: attn_bf16 = sum(o_w) / (sum(l_w) + 2^(sink*log2e)) ----------------
__global__ __launch_bounds__(256) void merge_k(const u16* __restrict__ obuf,
                                               const float* __restrict__ lbuf,
                                               const float* __restrict__ sink,
                                               u16* __restrict__ attnb) {
    int row = blockIdx.x;
    int c = row >> 4, cc = row & 15;
    int nw = (c >> 5) + 1;  // windows for this chunk
    int jb = (c < 32) ? c
           : (c < 64) ? 32 + ((c - 32) << 1)
           : (c < 96) ? 96 + 3 * (c - 64)
                      : 192 + ((c - 96) << 2);
    int t = threadIdx.x;
    int h = t >> 3, col0 = (t & 7) * 8;

    float acc[8] = {};
    float lsum = __builtin_amdgcn_exp2f(sink[h] * LOG2E);
#pragma unroll 1
    for (int w = 0; w < nw; ++w) {
        size_t slot = (size_t)h * 320 + jb + w;
        lsum += lbuf[slot * 16 + cc];
        u16x8 v = *reinterpret_cast<const u16x8*>(&obuf[slot * 1024 + cc * 64 + col0]);
#pragma unroll
        for (int i = 0; i < 8; ++i) acc[i] += bf2f(v[i]);
    }
    float inv = 1.f / lsum;
    u16x8 ob;
#pragma unroll
    for (int i = 0; i < 8; ++i) ob[i] = f2bf(acc[i] * inv);
    *reinterpret_cast<u16x8*>(&attnb[(size_t)row * 2048 + h * 64 + col0]) = ob;
}

extern "C" void kernel_launch(void* const* d_in, const int* in_sizes, int n_in,
                              void* d_out, int out_size, void* d_ws, size_t ws_size,
                              hipStream_t stream) {
    const float* x    = (const float*)d_in[0];
    const float* cosb = (const float*)d_in[2];
    const float* sinb = (const float*)d_in[3];
    const float* wq   = (const float*)d_in[4];
    const float* wk   = (const float*)d_in[5];
    const float* wv   = (const float*)d_in[6];
    const float* wo   = (const float*)d_in[7];
    const float* qw   = (const float*)d_in[8];
    const float* kw   = (const float*)d_in[9];
    const float* sink = (const float*)d_in[10];
    float* out = (float*)d_out;

    char* ws = (char*)d_ws;
    size_t off = 0;
    auto alloc = [&](size_t bytes) {
        char* p = ws + off;
        off += (bytes + 255) & ~(size_t)255;
        return p;
    };
    u16*   xb    = (u16*)alloc((size_t)2048 * 2048 * 2);
    u16*   wqkvt = (u16*)alloc((size_t)3072 * 2048 * 2);
    u16*   wot   = (u16*)alloc((size_t)2048 * 2048 * 2);
    float* qkv   = (float*)alloc((size_t)2048 * 3072 * 4);
    u16*   qnb   = (u16*)alloc((size_t)2048 * 2048 * 2);
    u16*   kfrag = (u16*)alloc((size_t)8 * 128 * 1024 * 2);
    u16*   vfrag = (u16*)alloc((size_t)8 * 64 * 2048 * 2);
    float* lbuf  = (float*)alloc((size_t)32 * 320 * 16 * 4);
    u16*   attnb = xb;              // xb dead after GEMM1
    u16*   obuf  = (u16*)qkv;       // qkv (25 MB) dead after norm_rope/v_frag; slots need 21 MB

    cast_bf16_k<<<2048, 256, 0, stream>>>(x, xb, 2048 * 2048 / 4);
    transpose_cast_k<<<dim3(32, 32), 256, 0, stream>>>(wq, wqkvt, 2048, 2048);
    transpose_cast_k<<<dim3(8, 32), 256, 0, stream>>>(wk, wqkvt + (size_t)2048 * 2048, 2048, 512);
    transpose_cast_k<<<dim3(8, 32), 256, 0, stream>>>(wv, wqkvt + (size_t)2560 * 2048, 2048, 512);
    transpose_cast_k<<<dim3(32, 32), 256, 0, stream>>>(wo, wot, 2048, 2048);

    gemm_bt_k<<<dim3(24, 16), 256, 0, stream>>>(xb, wqkvt, qkv, 2048, 3072, 2048);
    norm_rope_k<<<20480, 256, 0, stream>>>(qkv, cosb, sinb, qw, kw, qnb, kfrag);
    v_frag_k<<<dim3(32, 8), 256, 0, stream>>>(qkv, vfrag);

    attn_k<<<dim3(32, 80), 256, 0, stream>>>(qnb, kfrag, vfrag, obuf, lbuf);
    merge_k<<<2048, 256, 0, stream>>>(obuf, lbuf, sink, attnb);

    gemm_bt_k<<<dim3(16, 16), 256, 0, stream>>>(attnb, wot, out, 2048, 2048, 2048);
}

// Round 6
// 162.628 us; speedup vs baseline: 2.7690x; 1.1998x over previous
//
#include <hip/hip_runtime.h>

typedef unsigned short u16;
typedef __bf16 bf16;
typedef float f32x4 __attribute__((ext_vector_type(4)));
typedef bf16 bf16x8 __attribute__((ext_vector_type(8)));
typedef short s16x4 __attribute__((ext_vector_type(4)));
typedef u16 u16x4 __attribute__((ext_vector_type(4)));
typedef u16 u16x8 __attribute__((ext_vector_type(8)));

#define SEQ 2048
#define LOG2E 1.4426950408889634f

__device__ __forceinline__ u16 f2bf(float f) {
    return __builtin_bit_cast(u16, (bf16)f);
}
__device__ __forceinline__ float bf2f(u16 u) {
    unsigned int w = ((unsigned int)u) << 16;
    return __builtin_bit_cast(float, w);
}

// ---------------- cast f32 -> bf16 (vectorized) ----------------
__global__ __launch_bounds__(256) void cast_bf16_k(const float* __restrict__ in,
                                                   u16* __restrict__ out, int n4) {
    int i = blockIdx.x * 256 + threadIdx.x;
    int stride = gridDim.x * 256;
    for (; i < n4; i += stride) {
        float4 v = reinterpret_cast<const float4*>(in)[i];
        u16x4 o;
        o[0] = f2bf(v.x); o[1] = f2bf(v.y); o[2] = f2bf(v.z); o[3] = f2bf(v.w);
        reinterpret_cast<u16x4*>(out)[i] = o;
    }
}

// ---------------- transpose + cast: src f32 [R][C] -> dst bf16 [C][R] ----------------
__global__ __launch_bounds__(256) void transpose_cast_k(const float* __restrict__ src,
                                                        u16* __restrict__ dst, int R, int C) {
    __shared__ float t[64][65];
    int c0 = blockIdx.x * 64, r0 = blockIdx.y * 64;
    int tx = threadIdx.x & 63, ty = threadIdx.x >> 6;
#pragma unroll
    for (int i = 0; i < 16; ++i) {
        int r = ty + i * 4;
        t[r][tx] = src[(size_t)(r0 + r) * C + c0 + tx];
    }
    __syncthreads();
#pragma unroll
    for (int i = 0; i < 16; ++i) {
        int c = ty + i * 4;
        dst[(size_t)(c0 + c) * R + r0 + tx] = f2bf(t[tx][c]);
    }
}

// ---------------- GEMM partial: Cp[z][M,N](bf16) = A[M,kz] @ Bt[N,kz]^T ----------------
// 128x128 tile, BK=32, split-K (blockIdx.z), double-buffered LDS with prefetch,
// XOR-swizzled LDS slots (pre-swizzled gload_lds source + swizzled ds_read; rule #21).
__global__ __launch_bounds__(256) void gemm_bt_dbuf_k(const u16* __restrict__ A,
                                                      const u16* __restrict__ Bt,
                                                      u16* __restrict__ Cp,
                                                      int M, int N, int K) {
    __shared__ __align__(16) u16 As[2][128 * 32];
    __shared__ __align__(16) u16 Bs[2][128 * 32];
    int tid = threadIdx.x;
    int wave = tid >> 6, lane = tid & 63;
    int bm = blockIdx.y * 128, bn = blockIdx.x * 128;
    int z = blockIdx.z;
    int kt0 = z * (K >> 1), ktend = kt0 + (K >> 1);
    int wm = (wave >> 1) * 64, wn = (wave & 1) * 64;
    int g = lane >> 4, cidx = lane & 15;
    f32x4 acc[4][4] = {};

    // staging: LDS slot (srow, lane&3) holds global k-chunk (lane&3) ^ ((srow>>1)&3)
    int srow = lane >> 2;
    int skol = ((lane & 3) ^ ((srow >> 1) & 3)) * 8;
    // read: logical chunk g of row r lives at slot g ^ ((r_in16>>1)&3); r_in16 = cidx
    int sl8 = (g ^ ((cidx >> 1) & 3)) * 8;

#define STAGE(buf, kt)                                                                \
    {                                                                                 \
        _Pragma("unroll")                                                             \
        for (int j = 0; j < 2; ++j) {                                                 \
            const u16* gpa = A + (size_t)(bm + (wave * 2 + j) * 16 + srow) * K + (kt) + skol; \
            __builtin_amdgcn_global_load_lds(                                         \
                (__attribute__((address_space(1))) void*)gpa,                         \
                (__attribute__((address_space(3))) void*)&As[buf][(wave * 2 + j) * 512], \
                16, 0, 0);                                                            \
        }                                                                             \
        _Pragma("unroll")                                                             \
        for (int j = 0; j < 2; ++j) {                                                 \
            const u16* gpb = Bt + (size_t)(bn + (wave * 2 + j) * 16 + srow) * K + (kt) + skol; \
            __builtin_amdgcn_global_load_lds(                                         \
                (__attribute__((address_space(1))) void*)gpb,                         \
                (__attribute__((address_space(3))) void*)&Bs[buf][(wave * 2 + j) * 512], \
                16, 0, 0);                                                            \
        }                                                                             \
    }

    STAGE(0, kt0);
    asm volatile("s_waitcnt vmcnt(0)" ::: "memory");
    __syncthreads();

    int cur = 0;
#pragma unroll 1
    for (int kt = kt0; kt < ktend; kt += 32) {
        if (kt + 32 < ktend) STAGE(cur ^ 1, kt + 32);  // prefetch in flight across compute

        bf16x8 af[4], bfr[4];
#pragma unroll
        for (int mi = 0; mi < 4; ++mi)
            af[mi] = *reinterpret_cast<const bf16x8*>(&As[cur][(wm + mi * 16 + cidx) * 32 + sl8]);
#pragma unroll
        for (int ni = 0; ni < 4; ++ni)
            bfr[ni] = *reinterpret_cast<const bf16x8*>(&Bs[cur][(wn + ni * 16 + cidx) * 32 + sl8]);
#pragma unroll
        for (int mi = 0; mi < 4; ++mi)
#pragma unroll
            for (int ni = 0; ni < 4; ++ni)
                acc[mi][ni] = __builtin_amdgcn_mfma_f32_16x16x32_bf16(af[mi], bfr[ni], acc[mi][ni], 0, 0, 0);

        asm volatile("s_waitcnt vmcnt(0)" ::: "memory");
        __syncthreads();
        cur ^= 1;
    }
#undef STAGE

    u16* cbase = Cp + (size_t)z * M * N;
#pragma unroll
    for (int mi = 0; mi < 4; ++mi) {
#pragma unroll
        for (int r = 0; r < 4; ++r) {
            int row = bm + wm + mi * 16 + g * 4 + r;
            u16* cp = cbase + (size_t)row * N + bn + wn + cidx;
#pragma unroll
            for (int ni = 0; ni < 4; ++ni)
                cp[ni * 16] = f2bf(acc[mi][ni][r]);
        }
    }
}

// ---------------- sum two bf16 partials -> f32 ----------------
__global__ __launch_bounds__(256) void sum2_f32_k(const u16* __restrict__ a,
                                                  const u16* __restrict__ b,
                                                  float* __restrict__ out, int n8) {
    int i = blockIdx.x * 256 + threadIdx.x;
    if (i >= n8) return;
    u16x8 va = reinterpret_cast<const u16x8*>(a)[i];
    u16x8 vb = reinterpret_cast<const u16x8*>(b)[i];
    f32x4 lo, hi;
#pragma unroll
    for (int j = 0; j < 4; ++j) {
        lo[j] = bf2f(va[j]) + bf2f(vb[j]);
        hi[j] = bf2f(va[4 + j]) + bf2f(vb[4 + j]);
    }
    reinterpret_cast<f32x4*>(out)[i * 2] = lo;
    reinterpret_cast<f32x4*>(out)[i * 2 + 1] = hi;
}

// ---------------- RMSNorm + RoPE for Q and K heads (sums split-K partials) ----------------
// Q: pre-scaled by 0.125*log2(e) (exp2-base softmax), row-major [s][32*64]
// K: written in MFMA A-fragment order kfrag[kvh][kb=s>>4][g=d>>3][c=s&15][e=d&7]
__global__ __launch_bounds__(256) void norm_rope_k(const u16* __restrict__ p0,
                                                   const u16* __restrict__ p1,
                                                   const float* __restrict__ cosb,
                                                   const float* __restrict__ sinb,
                                                   const float* __restrict__ qw,
                                                   const float* __restrict__ kw,
                                                   u16* __restrict__ qn,
                                                   u16* __restrict__ kfrag) {
    int idx = blockIdx.x * 4 + (threadIdx.x >> 6);
    int lane = threadIdx.x & 63;
    int s = idx / 40, hh = idx - s * 40;
    size_t off = (hh < 32) ? ((size_t)s * 3072 + hh * 64 + lane)
                           : ((size_t)s * 3072 + 2048 + (hh - 32) * 64 + lane);
    float val = bf2f(p0[off]) + bf2f(p1[off]);
    float ss = val * val;
#pragma unroll
    for (int mm = 32; mm; mm >>= 1) ss += __shfl_xor(ss, mm);
    float w = (hh < 32) ? qw[lane] : kw[lane];
    float xn = val * rsqrtf(ss * (1.f / 64.f) + 1e-6f) * w;
    float part = __shfl_xor(xn, 32);
    float rot = (lane < 32) ? -part : part;
    float o = xn * cosb[s * 64 + lane] + rot * sinb[s * 64 + lane];
    if (hh < 32) {
        qn[(size_t)s * 2048 + hh * 64 + lane] = f2bf(o * (0.125f * LOG2E));
    } else {
        int h8 = hh - 32;
        kfrag[(((size_t)h8 * 128 + (s >> 4)) << 10) + (lane >> 3) * 128 + (s & 15) * 8 + (lane & 7)] = f2bf(o);
    }
}

// ---------------- V in packed PV A-fragment order (sums split-K partials) ----------------
// vfrag[kvh][kb32][dt][g][c][s2*4+i] = V[kb32*32 + s2*16 + g*4 + i][dt*16 + c]
__global__ __launch_bounds__(256) void v_frag_k(const u16* __restrict__ p0,
                                                const u16* __restrict__ p1,
                                                u16* __restrict__ vfrag) {
    __shared__ float t[64][65];
    int s0 = blockIdx.x * 64;
    int h = blockIdx.y;
    int tx = threadIdx.x & 63, ty = threadIdx.x >> 6;
#pragma unroll
    for (int i = 0; i < 16; ++i) {
        int r = ty + i * 4;
        size_t off = (size_t)(s0 + r) * 3072 + 2560 + h * 64 + tx;
        t[r][tx] = bf2f(p0[off]) + bf2f(p1[off]);
    }
    __syncthreads();
    int dt = threadIdx.x >> 6, g = (threadIdx.x >> 4) & 3, cc = threadIdx.x & 15;
#pragma unroll
    for (int kb2 = 0; kb2 < 4; ++kb2) {
        u16x4 o;
#pragma unroll
        for (int i = 0; i < 4; ++i) o[i] = f2bf(t[kb2 * 16 + g * 4 + i][dt * 16 + cc]);
        size_t idx = ((size_t)h * 64 + (s0 >> 5) + (kb2 >> 1)) * 2048 + dt * 512 + g * 128 + cc * 8 + (kb2 & 1) * 4;
        *reinterpret_cast<u16x4*>(&vfrag[idx]) = o;
    }
}

// ---------------- Flash attention: dense (chunk,window) wave enumeration ----------------
// Per head: 320 active waves, j -> (c,w) analytically (windows of 512 keys).
// Each wave writes a private 16x64 bf16 partial slot + 16 f32 l-partials (no atomics).
// NOTE: launch_bounds min-waves MUST stay <=4: (256,8) capped VGPR at 32 and
// spilled ~1.3 GB of scratch to HBM per dispatch (round-4 regression).
__global__ __launch_bounds__(256, 4) void attn_k(const u16* __restrict__ qn,
                                                 const u16* __restrict__ kfrag,
                                                 const u16* __restrict__ vfrag,
                                                 u16* __restrict__ obuf,
                                                 float* __restrict__ lbuf) {
    int h = blockIdx.x;
    int wave = threadIdx.x >> 6, lane = threadIdx.x & 63;
    int j = blockIdx.y * 4 + wave;   // 0..319
    int c, w;
    if (j < 32)       { c = j;                    w = 0; }
    else if (j < 96)  { c = 32 + ((j - 32) >> 1); w = (j - 32) & 1; }
    else if (j < 192) { int r = j - 96;  int q = r / 3; c = 64 + q; w = r - 3 * q; }
    else              { c = 96 + ((j - 192) >> 2); w = (j - 192) & 3; }

    int q0 = c * 16;
    int nk = q0 + 16;
    int kv0 = w * 512;
    int kvend = (kv0 + 512 < nk) ? (kv0 + 512) : nk;

    int kvh = h >> 2, g = lane >> 4, cc = lane & 15;
    int qrow = q0 + cc;

    const size_t qoff = (size_t)qrow * 2048 + h * 64;
    bf16x8 q_0 = *reinterpret_cast<const bf16x8*>(&qn[qoff + g * 8]);
    bf16x8 q_1 = *reinterpret_cast<const bf16x8*>(&qn[qoff + 32 + g * 8]);

    float l = 0.f;
    f32x4 o[4] = {};

    const u16* kbase = kfrag + (((size_t)kvh * 128) << 10) + lane * 8;
    const u16* vbase = vfrag + (size_t)kvh * 64 * 2048 + g * 128 + cc * 8;

    // preload K for first block
    bf16x8 kf0[4], kf1[4];
#pragma unroll
    for (int sub = 0; sub < 4; ++sub) {
        const u16* kp = kbase + (size_t)((kv0 >> 4) + sub) * 1024;
        kf0[sub] = *reinterpret_cast<const bf16x8*>(kp);
        kf1[sub] = *reinterpret_cast<const bf16x8*>(kp + 512);
    }

#pragma unroll 1
    for (; kv0 < kvend; kv0 += 64) {
        f32x4 st[4];
        __builtin_amdgcn_s_setprio(1);
#pragma unroll
        for (int sub = 0; sub < 4; ++sub) {
            st[sub] = __builtin_amdgcn_mfma_f32_16x16x32_bf16(kf0[sub], q_0, (f32x4){0.f, 0.f, 0.f, 0.f}, 0, 0, 0);
            st[sub] = __builtin_amdgcn_mfma_f32_16x16x32_bf16(kf1[sub], q_1, st[sub], 0, 0, 0);
        }
        __builtin_amdgcn_s_setprio(0);

        // K prefetch for next block (in-flight across softmax)
        if (kv0 + 64 < kvend) {
#pragma unroll
            for (int sub = 0; sub < 4; ++sub) {
                const u16* kp = kbase + (size_t)(((kv0 + 64) >> 4) + sub) * 1024;
                kf0[sub] = *reinterpret_cast<const bf16x8*>(kp);
                kf1[sub] = *reinterpret_cast<const bf16x8*>(kp + 512);
            }
        }

        // V loads for current block
        bf16x8 vv[2][4];
#pragma unroll
        for (int sp = 0; sp < 2; ++sp)
#pragma unroll
            for (int dt = 0; dt < 4; ++dt)
                vv[sp][dt] = *reinterpret_cast<const bf16x8*>(
                    vbase + (size_t)((kv0 >> 5) + sp) * 2048 + dt * 512);

        // causal mask (diagonal block only)
        if (kv0 + 64 > q0) {
#pragma unroll
            for (int sub = 0; sub < 4; ++sub)
#pragma unroll
                for (int r = 0; r < 4; ++r)
                    if (kv0 + sub * 16 + g * 4 + r > qrow) st[sub][r] = -1e30f;
        }

        // fixed-base softmax: weights = exp2(score'), no max tracking
        s16x4 pf[4];
        float rs = 0.f;
#pragma unroll
        for (int sub = 0; sub < 4; ++sub)
#pragma unroll
            for (int r = 0; r < 4; ++r) {
                float e = __builtin_amdgcn_exp2f(st[sub][r]);
                rs += e;
                pf[sub][r] = (short)f2bf(e);
            }
        l += rs;

        __builtin_amdgcn_s_setprio(1);
#pragma unroll
        for (int sp = 0; sp < 2; ++sp)
#pragma unroll
            for (int dt = 0; dt < 4; ++dt) {
                s16x4 vlo = __builtin_bit_cast(s16x4,
                    __builtin_shufflevector(vv[sp][dt], vv[sp][dt], 0, 1, 2, 3));
                s16x4 vhi = __builtin_bit_cast(s16x4,
                    __builtin_shufflevector(vv[sp][dt], vv[sp][dt], 4, 5, 6, 7));
                o[dt] = __builtin_amdgcn_mfma_f32_16x16x16bf16_1k(vlo, pf[sp * 2], o[dt], 0, 0, 0);
                o[dt] = __builtin_amdgcn_mfma_f32_16x16x16bf16_1k(vhi, pf[sp * 2 + 1], o[dt], 0, 0, 0);
            }
        __builtin_amdgcn_s_setprio(0);
    }

    // private-slot partial write (plain stores, no atomics)
    l += __shfl_xor(l, 16);
    l += __shfl_xor(l, 32);
    size_t slot = (size_t)h * 320 + j;
    if (lane < 16) lbuf[slot * 16 + cc] = l;
    u16* sp = obuf + slot * 1024;
#pragma unroll
    for (int dt = 0; dt < 4; ++dt) {
        u16x4 ov;
#pragma unroll
        for (int r = 0; r < 4; ++r) ov[r] = f2bf(o[dt][r]);
        *reinterpret_cast<u16x4*>(&sp[cc * 64 + dt * 16 + g * 4]) = ov;
    }
}

// ---------------- merge: attn_bf16 = sum(o_w) / (sum(l_w) + 2^(sink*log2e)) ----------------
__global__ __launch_bounds__(256) void merge_k(const u16* __restrict__ obuf,
                                               const float* __restrict__ lbuf,
                                               const float* __restrict__ sink,
                                               u16* __restrict__ attnb) {
    int row = blockIdx.x;
    int c = row >> 4, cc = row & 15;
    int nw = (c >> 5) + 1;  // windows for this chunk
    int jb = (c < 32) ? c
           : (c < 64) ? 32 + ((c - 32) << 1)
           : (c < 96) ? 96 + 3 * (c - 64)
                      : 192 + ((c - 96) << 2);
    int t = threadIdx.x;
    int h = t >> 3, col0 = (t & 7) * 8;

    float acc[8] = {};
    float lsum = __builtin_amdgcn_exp2f(sink[h] * LOG2E);
#pragma unroll 1
    for (int w = 0; w < nw; ++w) {
        size_t slot = (size_t)h * 320 + jb + w;
        lsum += lbuf[slot * 16 + cc];
        u16x8 v = *reinterpret_cast<const u16x8*>(&obuf[slot * 1024 + cc * 64 + col0]);
#pragma unroll
        for (int i = 0; i < 8; ++i) acc[i] += bf2f(v[i]);
    }
    float inv = 1.f / lsum;
    u16x8 ob;
#pragma unroll
    for (int i = 0; i < 8; ++i) ob[i] = f2bf(acc[i] * inv);
    *reinterpret_cast<u16x8*>(&attnb[(size_t)row * 2048 + h * 64 + col0]) = ob;
}

extern "C" void kernel_launch(void* const* d_in, const int* in_sizes, int n_in,
                              void* d_out, int out_size, void* d_ws, size_t ws_size,
                              hipStream_t stream) {
    const float* x    = (const float*)d_in[0];
    const float* cosb = (const float*)d_in[2];
    const float* sinb = (const float*)d_in[3];
    const float* wq   = (const float*)d_in[4];
    const float* wk   = (const float*)d_in[5];
    const float* wv   = (const float*)d_in[6];
    const float* wo   = (const float*)d_in[7];
    const float* qw   = (const float*)d_in[8];
    const float* kw   = (const float*)d_in[9];
    const float* sink = (const float*)d_in[10];
    float* out = (float*)d_out;

    char* ws = (char*)d_ws;
    size_t off = 0;
    auto alloc = [&](size_t bytes) {
        char* p = ws + off;
        off += (bytes + 255) & ~(size_t)255;
        return p;
    };
    u16*   xb    = (u16*)alloc((size_t)2048 * 2048 * 2);       // x bf16
    u16*   wqkvt = (u16*)alloc((size_t)3072 * 2048 * 2);       // [wq^T; wk^T; wv^T]
    u16*   wot   = (u16*)alloc((size_t)2048 * 2048 * 2);       // wo^T
    u16*   p0    = (u16*)alloc((size_t)2048 * 3072 * 2);       // GEMM1 partial z=0 (bf16)
    u16*   p1    = (u16*)alloc((size_t)2048 * 3072 * 2);       // GEMM1 partial z=1 (bf16)
    u16*   qnb   = (u16*)alloc((size_t)2048 * 2048 * 2);
    u16*   kfrag = (u16*)alloc((size_t)8 * 128 * 1024 * 2);
    u16*   vfrag = (u16*)alloc((size_t)8 * 64 * 2048 * 2);
    float* lbuf  = (float*)alloc((size_t)32 * 320 * 16 * 4);
    u16*   attnb = xb;        // xb dead after GEMM1
    u16*   obuf  = p0;        // p0+p1 (25.2 MB contiguous) dead after norm_rope/v_frag; obuf needs 21 MB
    u16*   o2p   = p0;        // obuf dead after merge_k; GEMM2 bf16 partials need 16.8 MB

    cast_bf16_k<<<2048, 256, 0, stream>>>(x, xb, 2048 * 2048 / 4);
    transpose_cast_k<<<dim3(32, 32), 256, 0, stream>>>(wq, wqkvt, 2048, 2048);
    transpose_cast_k<<<dim3(8, 32), 256, 0, stream>>>(wk, wqkvt + (size_t)2048 * 2048, 2048, 512);
    transpose_cast_k<<<dim3(8, 32), 256, 0, stream>>>(wv, wqkvt + (size_t)2560 * 2048, 2048, 512);
    transpose_cast_k<<<dim3(32, 32), 256, 0, stream>>>(wo, wot, 2048, 2048);

    gemm_bt_dbuf_k<<<dim3(24, 16, 2), 256, 0, stream>>>(xb, wqkvt, p0, 2048, 3072, 2048);
    norm_rope_k<<<20480, 256, 0, stream>>>(p0, p1, cosb, sinb, qw, kw, qnb, kfrag);
    v_frag_k<<<dim3(32, 8), 256, 0, stream>>>(p0, p1, vfrag);

    attn_k<<<dim3(32, 80), 256, 0, stream>>>(qnb, kfrag, vfrag, obuf, lbuf);
    merge_k<<<2048, 256, 0, stream>>>(obuf, lbuf, sink, attnb);

    gemm_bt_dbuf_k<<<dim3(16, 16, 2), 256, 0, stream>>>(attnb, wot, o2p, 2048, 2048, 2048);
    sum2_f32_k<<<2048, 256, 0, stream>>>(o2p, o2p + (size_t)2048 * 2048, out, 2048 * 2048 / 8);
}